// Round 13
// baseline (306.860 us; speedup 1.0000x reference)
//
#include <hip/hip_runtime.h>
#include <hip/hip_bf16.h>

typedef __bf16 bf16;
typedef __attribute__((ext_vector_type(8))) __bf16 bf16x8;
typedef __attribute__((ext_vector_type(4))) __bf16 bf16x4;
typedef __attribute__((ext_vector_type(16))) float f32x16;

#define N_ROWS 16384
#define DIM 256
#define NT 128            /* 128-row tiles */
#define NJC 512           /* 32-col tiles */
#define LSTRIP 8
#define NSTRIPS 4160      /* sum_{it=0..127} ceil((512-4it)/8) */
#define SQK1 4.53981608f  /* sqrt(1/(0.07*ln2)): A pre-scaled so e^{z} = 2^{dot'} */
#define LN2F 0.69314718056f

#define WS_T_OFF (N_ROWS * DIM * 2)
#define WS_D_OFF (WS_T_OFF + N_ROWS * 4)
#define WS_DONE_OFF (WS_D_OFF + N_ROWS * 4)

#define GLOAD_LDS(g, l)                                        \
    __builtin_amdgcn_global_load_lds(                          \
        (const __attribute__((address_space(1))) void*)(g),    \
        (__attribute__((address_space(3))) void*)(l), 16, 0, 0)

// Kernel 1: L2-normalize rows, scale by SQK1, emit bf16 A' to ws. Zeros T[],
// done-counter, d_out. Dg[row] = s2' = sum(bf16(SQK1*a)^2) = the MFMA
// diagonal, so its bf16 rounding cancels: loss_i = ln2*(log2(T'_i) - s2'_i).
__global__ void __launch_bounds__(256) normalize_kernel(const float* __restrict__ in,
                                                        bf16* __restrict__ out,
                                                        float* __restrict__ Tg,
                                                        float* __restrict__ Dg,
                                                        int* __restrict__ done,
                                                        float* __restrict__ loss_out) {
    if (blockIdx.x == 0 && threadIdx.x == 0) { loss_out[0] = 0.0f; done[0] = 0; }
    if (blockIdx.x < 64) Tg[blockIdx.x * 256 + threadIdx.x] = 0.0f;

    const int row  = blockIdx.x * 4 + (threadIdx.x >> 6);
    const int lane = threadIdx.x & 63;
    const float4* rp = (const float4*)(in + (size_t)row * DIM);
    float4 v = rp[lane];
    float ss = v.x * v.x + v.y * v.y + v.z * v.z + v.w * v.w;
#pragma unroll
    for (int m = 1; m < 64; m <<= 1) ss += __shfl_xor(ss, m, 64);
    float inv = SQK1 / fmaxf(sqrtf(ss), 1e-12f);
    bf16x4 o;
    o[0] = (bf16)(v.x * inv);
    o[1] = (bf16)(v.y * inv);
    o[2] = (bf16)(v.z * inv);
    o[3] = (bf16)(v.w * inv);
    *(bf16x4*)(out + (size_t)row * DIM + lane * 4) = o;

    float f0 = (float)o[0], f1 = (float)o[1], f2 = (float)o[2], f3 = (float)o[3];
    float s2 = f0 * f0 + f1 * f1 + f2 * f2 + f3 * f3;
#pragma unroll
    for (int m = 1; m < 64; m <<= 1) s2 += __shfl_xor(s2, m, 64);
    if (lane == 0) Dg[row] = s2;
}

// Tree-reduce 16 floats across the 32 `lo` lanes; every lane ends with the
// full sum for register index r = (lo>>1)&15. (Correctness-proven R4-R12.)
#define TREE16(R, out)                                                     \
    do {                                                                   \
        float w8[8], w4[4], w2[2], w1, g_;                                 \
        _Pragma("unroll") for (int i_ = 0; i_ < 8; ++i_) {                 \
            g_ = (lo & 16) ? R[i_] : R[i_ + 8];                            \
            w8[i_] = ((lo & 16) ? R[i_ + 8] : R[i_]) + __shfl_xor(g_, 16); \
        }                                                                  \
        _Pragma("unroll") for (int i_ = 0; i_ < 4; ++i_) {                 \
            g_ = (lo & 8) ? w8[i_] : w8[i_ + 4];                           \
            w4[i_] = ((lo & 8) ? w8[i_ + 4] : w8[i_]) + __shfl_xor(g_, 8); \
        }                                                                  \
        _Pragma("unroll") for (int i_ = 0; i_ < 2; ++i_) {                 \
            g_ = (lo & 4) ? w4[i_] : w4[i_ + 2];                           \
            w2[i_] = ((lo & 4) ? w4[i_ + 2] : w4[i_]) + __shfl_xor(g_, 4); \
        }                                                                  \
        g_ = (lo & 2) ? w2[0] : w2[1];                                     \
        w1 = ((lo & 2) ? w2[1] : w2[0]) + __shfl_xor(g_, 2);               \
        out = w1 + __shfl_xor(w1, 1);                                      \
    } while (0)

// Kernel 2: symmetric A'A'^T + softmax denominator + fused final loss.
// 256 thr = 4 waves = 4 rg x 32 rows over a 128x32 tile. HYBRID B delivery:
// K-half [0,128) staged to LDS (8 KB/tile, DMA + swizzled b128 reads);
// K-half [128,256) read per-wave from GLOBAL (L1 — 4 waves share lines)
// with a depth-4 rotating register prefetch. This splits the fragment
// stream across the DS pipe and the L1 pipe (R11 was DS-throughput bound:
// 12 DS-cyc/read vs 8 MFMA-cyc over 4 SIMDs). ~134 unified regs ->
// 3 independent blocks/CU. vmcnt: DMAs issued at tile top BEFORE the
// tile's rotating loads; in-order retirement (m135) means vmcnt(2) drains
// all but the 2 newest (= the fresh DMAs), which barrier-2 publishes on
// the NEXT iteration.
__global__ void __launch_bounds__(256, 3)
loss_kernel(const bf16* __restrict__ A, float* __restrict__ Tg,
            const float* __restrict__ Dg, int* __restrict__ done,
            float* __restrict__ loss_out) {
    __shared__ bf16 Bs0[32 * 128];          // 8 KB (32 cols x K-half 128)
    __shared__ bf16 Bs1[32 * 128];          // 8 KB
    __shared__ float CsAcc[4][LSTRIP][32];  // 4 KB
    __shared__ float red2[4];
    __shared__ int lastflag;

    const int tid = threadIdx.x;
    const int w  = tid >> 6;   // = rg: rows w*32..+31
    const int l  = tid & 63;
    const int lo = l & 31, hi = l >> 5;

    // strip decode: (it, chunk of up to 8 col-tiles starting at jc0 >= 4*it)
    int it = 0, rem = blockIdx.x;
    for (;;) {
        int nch = (NJC - 4 * it + LSTRIP - 1) >> 3;
        if (rem < nch) break;
        rem -= nch;
        ++it;
    }
    const int jc0 = 4 * it + rem * LSTRIP;
    const int jc1 = (jc0 + LSTRIP < NJC) ? (jc0 + LSTRIP) : NJC;

    // persistent A fragments, full K=256 (A-op: m=lo, k=hi*8+j); static idx
    bf16x8 af[16];
    {
        const bf16* ap = A + (size_t)(it * 128 + w * 32 + lo) * DIM + hi * 8;
#pragma unroll
        for (int k = 0; k < 16; ++k)
            af[k] = *(const bf16x8*)(ap + k * 16);
    }

    float s0[16];
#pragma unroll
    for (int r = 0; r < 16; ++r) s0[r] = 0.f;

    // zero per-strip col accumulator (4*8*32 floats, 256 thr -> 4 each)
    for (int i = tid; i < 4 * LSTRIP * 32; i += 256) ((float*)CsAcc)[i] = 0.f;
    __syncthreads();

    // DMA lane constants: wave w stages B-tile rows w*8..+7 in 2 instrs
    // (4 rows each). Lane: rl2 = l>>4 (row in quad), s = l&15 (slot).
    // Slot s of row r holds global chunk c = (s&8)|((s&7)^(r&7)).
    const int s_dma = l & 15;
    const int rl2   = l >> 4;
    int vo[2];
#pragma unroll
    for (int q = 0; q < 2; ++q) {
        const int c = (s_dma & 8) | ((s_dma & 7) ^ ((q * 4 + rl2) & 7));
        vo[q] = rl2 * DIM + c * 8;
    }

    const int mx7 = lo & 7;
    const int lbase = lo * 128;  // LDS row base (elems)

    // global-half stream: chunk cc = 16 + 2j + hi, j = 0..7
    const bf16* gb = A + (size_t)(jc0 * 32 + lo) * DIM + 128 + hi * 8;
    bf16x8 buf[4];
#pragma unroll
    for (int q = 0; q < 4; ++q) buf[q] = *(const bf16x8*)(gb + 16 * q);

#define ISSUE(jcn, BUF)                                                      \
    do {                                                                     \
        const bf16* tb_ = A + (size_t)((jcn) * 32 + w * 8) * DIM;            \
        _Pragma("unroll") for (int q_ = 0; q_ < 2; ++q_) {                   \
            GLOAD_LDS(tb_ + (q_ * 4) * DIM + vo[q_],                         \
                      &BUF[(w * 8 + q_ * 4) * 128]);                         \
        }                                                                    \
    } while (0)

#define TILE_BODY(BR, BW, jc, t)                                             \
    do {                                                                     \
        asm volatile("s_barrier" ::: "memory");                              \
        if ((jc) + 1 < jc1) {                                                \
            ISSUE((jc) + 1, BW);                                             \
            asm volatile("s_waitcnt vmcnt(2)" ::: "memory");                 \
        } else {                                                             \
            asm volatile("s_waitcnt vmcnt(0)" ::: "memory");                 \
        }                                                                    \
        asm volatile("s_barrier" ::: "memory");                              \
        const bf16* gbn_ = gb + 32 * DIM;                                    \
        f32x16 c0;                                                           \
        _Pragma("unroll") for (int r_ = 0; r_ < 16; ++r_) c0[r_] = 0.f;      \
        /* K-half 1 from LDS (swizzled b128) */                              \
        _Pragma("unroll") for (int k_ = 0; k_ < 8; ++k_) {                   \
            const int cc_ = k_ * 2 + hi;                                     \
            const int slot_ = (cc_ & 8) | ((cc_ & 7) ^ mx7);                 \
            bf16x8 b_ = *(const bf16x8*)&BR[lbase + slot_ * 8];              \
            c0 = __builtin_amdgcn_mfma_f32_32x32x16_bf16(af[k_], b_, c0, 0, 0, 0); \
        }                                                                    \
        /* K-half 2 from global regs, depth-4 rotating prefetch */           \
        _Pragma("unroll") for (int j_ = 0; j_ < 8; ++j_) {                   \
            bf16x8 b_ = buf[j_ & 3];                                         \
            const bf16* pf_ = (j_ < 4) ? (gb + 16 * (j_ + 4))                \
                                       : (gbn_ + 16 * (j_ - 4));             \
            buf[j_ & 3] = *(const bf16x8*)pf_;                               \
            c0 = __builtin_amdgcn_mfma_f32_32x32x16_bf16(af[8 + j_], b_, c0, 0, 0, 0); \
        }                                                                    \
        gb = gbn_;                                                           \
        float cs_ = 0.f;                                                     \
        _Pragma("unroll") for (int r_ = 0; r_ < 16; ++r_) {                  \
            float e_ = __builtin_amdgcn_exp2f(c0[r_]);                       \
            s0[r_] += e_;                                                    \
            cs_ += e_;                                                       \
        }                                                                    \
        cs_ += __shfl_xor(cs_, 32);                                          \
        if (hi == 0) CsAcc[w][t][lo] = cs_ + CsAcc[w][t][lo] * 0.0f;         \
    } while (0)

    ISSUE(jc0, Bs0);
    int jc = jc0;
    while (jc < jc1) {
        TILE_BODY(Bs0, Bs1, jc, jc - jc0);
        ++jc;
        if (jc >= jc1) break;
        TILE_BODY(Bs1, Bs0, jc, jc - jc0);
        ++jc;
    }

    // strip end: row sums. C/D row = (r&3)+8*(r>>2)+4*hi.
    float t0;
    TREE16(s0, t0);
    const int r = (lo >> 1) & 15;
    const int rowoff = (r & 3) + 8 * (r >> 2) + 4 * hi;
    if ((l & 1) == 0)
        atomicAdd(&Tg[it * 128 + w * 32 + rowoff], t0);

    // col-sum flush (skip col-tiles inside the diagonal 128x128 super-tile:
    // jc>>2 == it — those cols are covered by the transposed row sums).
    __syncthreads();
    const int nt_strip = jc1 - jc0;
    for (int i = tid; i < nt_strip * 32; i += 256) {
        const int t = i >> 5, col = i & 31;
        if (((jc0 + t) >> 2) != it)
            atomicAdd(&Tg[(jc0 + t) * 32 + col],
                      CsAcc[0][t][col] + CsAcc[1][t][col] +
                      CsAcc[2][t][col] + CsAcc[3][t][col]);
    }

    // ---- last-block final reduction (fused; R12-proven correct) ----
    __syncthreads();
    if (tid == 0) {
        int old = __hip_atomic_fetch_add(done, 1, __ATOMIC_ACQ_REL,
                                         __HIP_MEMORY_SCOPE_AGENT);
        lastflag = (old == NSTRIPS - 1);
    }
    __syncthreads();
    if (lastflag) {
        float acc = 0.f;
        for (int i = tid; i < N_ROWS; i += 256) {
            float t = __hip_atomic_load(&Tg[i], __ATOMIC_RELAXED,
                                        __HIP_MEMORY_SCOPE_AGENT);
            acc += __log2f(t) - Dg[i];
        }
#pragma unroll
        for (int m = 1; m < 64; m <<= 1) acc += __shfl_xor(acc, m, 64);
        if (l == 0) red2[w] = acc;
        __syncthreads();
        if (tid == 0) {
            float s = red2[0] + red2[1] + red2[2] + red2[3];
            loss_out[0] = LN2F * s * (1.0f / (float)N_ROWS);
        }
    }
#undef ISSUE
#undef TILE_BODY
}

extern "C" void kernel_launch(void* const* d_in, const int* in_sizes, int n_in,
                              void* d_out, int out_size, void* d_ws, size_t ws_size,
                              hipStream_t stream) {
    const float* emb = (const float*)d_in[0];
    float* out = (float*)d_out;
    bf16* Abf = (bf16*)d_ws;
    float* Tg = (float*)((char*)d_ws + WS_T_OFF);
    float* Dg = (float*)((char*)d_ws + WS_D_OFF);
    int* done = (int*)((char*)d_ws + WS_DONE_OFF);

    hipLaunchKernelGGL(normalize_kernel, dim3(N_ROWS / 4), dim3(256), 0, stream,
                       emb, Abf, Tg, Dg, done, out);
    hipLaunchKernelGGL(loss_kernel, dim3(NSTRIPS), dim3(256), 0, stream,
                       Abf, Tg, Dg, done, out);
}

// Round 14
// 208.739 us; speedup vs baseline: 1.4701x; 1.4701x over previous
//
#include <hip/hip_runtime.h>
#include <hip/hip_bf16.h>

typedef __bf16 bf16;
typedef __attribute__((ext_vector_type(8))) __bf16 bf16x8;
typedef __attribute__((ext_vector_type(4))) __bf16 bf16x4;
typedef __attribute__((ext_vector_type(16))) float f32x16;

#define N_ROWS 16384
#define DIM 256
#define NT 128            /* 128-row tiles */
#define NJC 256           /* 64-col tiles */
#define LSTRIP 8
#define NSTRIPS 2112      /* sum_{it} ceil((256-2it)/8) */
#define SQK1 4.53981608f  /* sqrt(1/(0.07*ln2)): A pre-scaled so e^{z} = 2^{dot'} */
#define LN2F 0.69314718056f

#define WS_T_OFF (N_ROWS * DIM * 2)
#define WS_D_OFF (WS_T_OFF + N_ROWS * 4)
#define WS_DONE_OFF (WS_D_OFF + N_ROWS * 4)

#define GLOAD_LDS(g, l)                                        \
    __builtin_amdgcn_global_load_lds(                          \
        (const __attribute__((address_space(1))) void*)(g),    \
        (__attribute__((address_space(3))) void*)(l), 16, 0, 0)

// Kernel 1: L2-normalize rows, scale by SQK1, emit bf16 A' to ws. Zeros T[],
// done-counter, d_out. Dg[row] = s2' = sum(bf16(SQK1*a)^2) = the MFMA
// diagonal, so its bf16 rounding cancels: loss_i = ln2*(log2(T'_i) - s2'_i).
__global__ void __launch_bounds__(256) normalize_kernel(const float* __restrict__ in,
                                                        bf16* __restrict__ out,
                                                        float* __restrict__ Tg,
                                                        float* __restrict__ Dg,
                                                        int* __restrict__ done,
                                                        float* __restrict__ loss_out) {
    if (blockIdx.x == 0 && threadIdx.x == 0) { loss_out[0] = 0.0f; done[0] = 0; }
    if (blockIdx.x < 64) Tg[blockIdx.x * 256 + threadIdx.x] = 0.0f;

    const int row  = blockIdx.x * 4 + (threadIdx.x >> 6);
    const int lane = threadIdx.x & 63;
    const float4* rp = (const float4*)(in + (size_t)row * DIM);
    float4 v = rp[lane];
    float ss = v.x * v.x + v.y * v.y + v.z * v.z + v.w * v.w;
#pragma unroll
    for (int m = 1; m < 64; m <<= 1) ss += __shfl_xor(ss, m, 64);
    float inv = SQK1 / fmaxf(sqrtf(ss), 1e-12f);
    bf16x4 o;
    o[0] = (bf16)(v.x * inv);
    o[1] = (bf16)(v.y * inv);
    o[2] = (bf16)(v.z * inv);
    o[3] = (bf16)(v.w * inv);
    *(bf16x4*)(out + (size_t)row * DIM + lane * 4) = o;

    float f0 = (float)o[0], f1 = (float)o[1], f2 = (float)o[2], f3 = (float)o[3];
    float s2 = f0 * f0 + f1 * f1 + f2 * f2 + f3 * f3;
#pragma unroll
    for (int m = 1; m < 64; m <<= 1) s2 += __shfl_xor(s2, m, 64);
    if (lane == 0) Dg[row] = s2;
}

// Tree-reduce 16 floats across the 32 `lo` lanes; every lane ends with the
// full sum for register index r = (lo>>1)&15. (Correctness-proven R4-R13.)
#define TREE16(R, out)                                                     \
    do {                                                                   \
        float w8[8], w4[4], w2[2], w1, g_;                                 \
        _Pragma("unroll") for (int i_ = 0; i_ < 8; ++i_) {                 \
            g_ = (lo & 16) ? R[i_] : R[i_ + 8];                            \
            w8[i_] = ((lo & 16) ? R[i_ + 8] : R[i_]) + __shfl_xor(g_, 16); \
        }                                                                  \
        _Pragma("unroll") for (int i_ = 0; i_ < 4; ++i_) {                 \
            g_ = (lo & 8) ? w8[i_] : w8[i_ + 4];                           \
            w4[i_] = ((lo & 8) ? w8[i_ + 4] : w8[i_]) + __shfl_xor(g_, 8); \
        }                                                                  \
        _Pragma("unroll") for (int i_ = 0; i_ < 2; ++i_) {                 \
            g_ = (lo & 4) ? w4[i_] : w4[i_ + 2];                           \
            w2[i_] = ((lo & 4) ? w4[i_ + 2] : w4[i_]) + __shfl_xor(g_, 4); \
        }                                                                  \
        g_ = (lo & 2) ? w2[0] : w2[1];                                     \
        w1 = ((lo & 2) ? w2[1] : w2[0]) + __shfl_xor(g_, 2);               \
        out = w1 + __shfl_xor(w1, 1);                                      \
    } while (0)

// Kernel 2: R11's proven core (loss 112 µs) + R12's two validated wins.
// 512 thr = 8 waves = 4 rg(32 rows) x 2 cg(32 cols) per 128x64 tile.
// af persistent in AGPRs (plain loads — remat across the asm memory-clobber
// barriers is illegal; R12 confirmed no remat). B staged to LDS dbuf via
// global_load_lds w=16 + XOR source swizzle; raw s_barrier + vmcnt(4)
// (the ONLY outstanding vmem ops are DMAs, so vmcnt(4) keeps exactly the
// next tile's 4 DMAs in flight — R13's mixing of global loads broke this).
// Per-wave single-writer CsAcc (R11); fused last-block final reduction (R12).
__global__ void __launch_bounds__(512, 4)
loss_kernel(const bf16* __restrict__ A, float* __restrict__ Tg,
            const float* __restrict__ Dg, int* __restrict__ done,
            float* __restrict__ loss_out) {
    __shared__ bf16 Bs0[64 * DIM];          // 32 KB
    __shared__ bf16 Bs1[64 * DIM];          // 32 KB
    __shared__ float CsAcc[4][LSTRIP][64];  // 8 KB
    __shared__ float red2[8];
    __shared__ int lastflag;

    const int tid = threadIdx.x;
    const int w  = tid >> 6;
    const int l  = tid & 63;
    const int lo = l & 31, hi = l >> 5;
    const int rg = w >> 1;   // row-group: rows rg*32..+31
    const int cg = w & 1;    // col-group: cols cg*32..+31

    // strip decode: (it, chunk of up to 8 col-tiles starting at jc0 >= 2*it)
    int it = 0, rem = blockIdx.x;
    for (;;) {
        int nch = (NJC - 2 * it + LSTRIP - 1) >> 3;
        if (rem < nch) break;
        rem -= nch;
        ++it;
    }
    const int jc0 = 2 * it + rem * LSTRIP;
    const int jc1 = (jc0 + LSTRIP < NJC) ? (jc0 + LSTRIP) : NJC;

    // persistent A fragments (A-op: m=lo, k=hi*8+j); plain loads, static idx
    bf16x8 af[16];
    {
        const bf16* ap = A + (size_t)(it * 128 + rg * 32 + lo) * DIM + hi * 8;
#pragma unroll
        for (int k = 0; k < 16; ++k)
            af[k] = *(const bf16x8*)(ap + k * 16);
    }

    float s0[16];
#pragma unroll
    for (int r = 0; r < 16; ++r) s0[r] = 0.f;

    // DMA lane constants (wave w stages B rows w*8..+7 in 4 instrs, 2 rows
    // each; slot s of row r holds global chunk c = (s&24)|((s&7)^(r&7)))
    const int s_dma = l & 31;
    const int rl    = l >> 5;
    int vo[4];
#pragma unroll
    for (int q = 0; q < 4; ++q) {
        const int c = (s_dma & 24) | ((s_dma & 7) ^ ((q * 2 + rl) & 7));
        vo[q] = rl * DIM + c * 8;
    }

    const int rbase = (cg * 32 + lo) * DIM;
    const int mx7 = lo & 7;

#define ISSUE(jcn, BUF)                                                      \
    do {                                                                     \
        const bf16* tb_ = A + (size_t)((jcn) * 64 + w * 8) * DIM;            \
        bf16* lb_ = &BUF[(w * 8) * DIM];                                     \
        _Pragma("unroll") for (int q_ = 0; q_ < 4; ++q_) {                   \
            GLOAD_LDS(tb_ + (q_ * 2) * DIM + vo[q_],                         \
                      lb_ + (q_ * 2) * DIM);                                 \
        }                                                                    \
    } while (0)

#define TILE_BODY(BR, BW, jc, t)                                             \
    do {                                                                     \
        asm volatile("s_barrier" ::: "memory");                              \
        if ((jc) + 1 < jc1) {                                                \
            ISSUE((jc) + 1, BW);                                             \
            asm volatile("s_waitcnt vmcnt(4)" ::: "memory");                 \
        } else {                                                             \
            asm volatile("s_waitcnt vmcnt(0)" ::: "memory");                 \
        }                                                                    \
        asm volatile("s_barrier" ::: "memory");                              \
        f32x16 c0;                                                           \
        _Pragma("unroll") for (int r_ = 0; r_ < 16; ++r_) c0[r_] = 0.f;      \
        _Pragma("unroll") for (int k_ = 0; k_ < 16; ++k_) {                  \
            const int cc_ = k_ * 2 + hi;                                     \
            const int slot_ = (cc_ & 24) | ((cc_ & 7) ^ mx7);                \
            bf16x8 b_ = *(const bf16x8*)&BR[rbase + slot_ * 8];              \
            c0 = __builtin_amdgcn_mfma_f32_32x32x16_bf16(af[k_], b_, c0, 0, 0, 0); \
        }                                                                    \
        float cs_ = 0.f;                                                     \
        _Pragma("unroll") for (int r_ = 0; r_ < 16; ++r_) {                  \
            float e_ = __builtin_amdgcn_exp2f(c0[r_]);                       \
            s0[r_] += e_;                                                    \
            cs_ += e_;                                                       \
        }                                                                    \
        cs_ += __shfl_xor(cs_, 32);                                          \
        if (hi == 0) CsAcc[rg][t][cg * 32 + lo] = cs_;                       \
    } while (0)

    ISSUE(jc0, Bs0);
    int jc = jc0;
    while (jc < jc1) {
        TILE_BODY(Bs0, Bs1, jc, jc - jc0);
        ++jc;
        if (jc >= jc1) break;
        TILE_BODY(Bs1, Bs0, jc, jc - jc0);
        ++jc;
    }

    // strip end: row sums. C/D row = (r&3)+8*(r>>2)+4*hi.
    float t0;
    TREE16(s0, t0);
    const int r = (lo >> 1) & 15;
    const int rowoff = (r & 3) + 8 * (r >> 2) + 4 * hi;
    if ((l & 1) == 0)
        atomicAdd(&Tg[it * 128 + rg * 32 + rowoff], t0);

    // col-sum flush (skip the diagonal 128x128 super-tile: jc>>1 == it)
    __syncthreads();
    const int nt_strip = jc1 - jc0;
    for (int i = tid; i < nt_strip * 64; i += 512) {
        const int t = i >> 6, col = i & 63;
        if (((jc0 + t) >> 1) != it)
            atomicAdd(&Tg[(jc0 + t) * 64 + col],
                      CsAcc[0][t][col] + CsAcc[1][t][col] +
                      CsAcc[2][t][col] + CsAcc[3][t][col]);
    }

    // ---- last-block final reduction (fused; R12-proven correct) ----
    __syncthreads();
    if (tid == 0) {
        int old = __hip_atomic_fetch_add(done, 1, __ATOMIC_ACQ_REL,
                                         __HIP_MEMORY_SCOPE_AGENT);
        lastflag = (old == NSTRIPS - 1);
    }
    __syncthreads();
    if (lastflag) {
        float acc = 0.f;
        for (int i = tid; i < N_ROWS; i += 512) {
            float t = __hip_atomic_load(&Tg[i], __ATOMIC_RELAXED,
                                        __HIP_MEMORY_SCOPE_AGENT);
            acc += __log2f(t) - Dg[i];
        }
#pragma unroll
        for (int m = 1; m < 64; m <<= 1) acc += __shfl_xor(acc, m, 64);
        if (l == 0) red2[w] = acc;
        __syncthreads();
        if (tid == 0) {
            float s = red2[0] + red2[1] + red2[2] + red2[3] +
                      red2[4] + red2[5] + red2[6] + red2[7];
            loss_out[0] = LN2F * s * (1.0f / (float)N_ROWS);
        }
    }
#undef ISSUE
#undef TILE_BODY
}

extern "C" void kernel_launch(void* const* d_in, const int* in_sizes, int n_in,
                              void* d_out, int out_size, void* d_ws, size_t ws_size,
                              hipStream_t stream) {
    const float* emb = (const float*)d_in[0];
    float* out = (float*)d_out;
    bf16* Abf = (bf16*)d_ws;
    float* Tg = (float*)((char*)d_ws + WS_T_OFF);
    float* Dg = (float*)((char*)d_ws + WS_D_OFF);
    int* done = (int*)((char*)d_ws + WS_DONE_OFF);

    hipLaunchKernelGGL(normalize_kernel, dim3(N_ROWS / 4), dim3(256), 0, stream,
                       emb, Abf, Tg, Dg, done, out);
    hipLaunchKernelGGL(loss_kernel, dim3(NSTRIPS), dim3(512), 0, stream,
                       Abf, Tg, Dg, done, out);
}